// Round 12
// baseline (296.887 us; speedup 1.0000x reference)
//
#include <hip/hip_runtime.h>

static constexpr int VD = 16;     // vertex feature dim
static constexpr int SD = 64;     // state dim
static constexpr int ED = 16;     // edge feature dim
static constexpr int RH = 10, RD = 32;
static constexpr int N_ITERS = 3;

typedef __attribute__((ext_vector_type(8))) short short8;
typedef __attribute__((ext_vector_type(4))) float floatx4;

__device__ __forceinline__ float sigmoid_f(float x) {
    return 1.f / (1.f + __expf(-x));
}
__device__ __forceinline__ float tanh_f(float x) {
    x = fminf(fmaxf(x, -20.f), 20.f);
    float e = __expf(2.f * x);
    return (e - 1.f) / (e + 1.f);
}
__device__ __forceinline__ unsigned short f2bf(float x) {   // round-to-nearest-even
    unsigned u = __float_as_uint(x);
    unsigned r = (u + 0x7FFFu + ((u >> 16) & 1u)) >> 16;
    return (unsigned short)r;
}
__device__ __forceinline__ float bf2f(unsigned short s) {
    return __uint_as_float(((unsigned)s) << 16);
}
__device__ __forceinline__ float bflo(unsigned u) { return __uint_as_float(u << 16); }
__device__ __forceinline__ float bfhi(unsigned u) { return __uint_as_float(u & 0xFFFF0000u); }

// Fused: one-time bf16 weight transposes (blocks 0..95) + degree histogram (blocks 96..).
__global__ void prep_hist_kernel(const float* __restrict__ W_msg,
                                 const float* __restrict__ W_i, const float* __restrict__ W_h,
                                 const float* __restrict__ W_embed,
                                 unsigned short* __restrict__ WabT, unsigned short* __restrict__ WiT,
                                 unsigned short* __restrict__ WhT, unsigned short* __restrict__ W3T,
                                 unsigned short* __restrict__ WeT,
                                 const int* __restrict__ edge_dst, int* __restrict__ deg,
                                 int n_edges) {
    if ((int)blockIdx.x < 96) {              // 96*256 = 24576 = total weight elems
        int i = blockIdx.x * 256 + threadIdx.x;
        if (i < 128*64) {                    // WabT[n][k]: n<64 -> W1 col n; else W2 col n-64
            int n = i >> 6, k = i & 63;
            WabT[i] = f2bf(W_msg[((n < 64 ? 0 : 64) + k)*64 + (n & 63)]);
        }
        int j = i - 128*64;
        if (j >= 0 && j < 192*64) {          // WiT/WhT[n][k] = W[k][n]
            int n = j >> 6, k = j & 63;
            WiT[j] = f2bf(W_i[k*192 + n]);
            WhT[j] = f2bf(W_h[k*192 + n]);
        }
        int l = i - 128*64 - 192*64;
        if (l >= 0 && l < 64*32) {           // W3T[n][k], k padded 16->32 with zeros
            int n = l >> 5, k = l & 31;
            W3T[l] = (k < 16) ? f2bf(W_msg[(128+k)*64 + n]) : (unsigned short)0;
        }
        int m = i - 128*64 - 192*64 - 64*32;
        if (m >= 0 && m < 64*32) {           // WeT[n][k], k padded 16->32 (embed)
            int n = m >> 5, k = m & 31;
            WeT[m] = (k < 16) ? f2bf(W_embed[k*64 + n]) : (unsigned short)0;
        }
    } else {
        int e = ((int)blockIdx.x - 96) * 256 + threadIdx.x;
        if (e < n_edges) atomicAdd(&deg[edge_dst[e]], 1);
    }
}

// Exclusive scan of EVEN-PADDED degrees -> row_ptr. Single block, shuffle-based.
// (1 dispatch instead of 3: per-dispatch overhead > the extra in-kernel work.)
__global__ __launch_bounds__(1024) void scan_kernel(const int* __restrict__ deg,
                                                    int* __restrict__ row_ptr,
                                                    int n_nodes) {
    __shared__ int wsum[16];
    int lid = threadIdx.x, lane = lid & 63, wv = lid >> 6;
    int C = (n_nodes + 1023) >> 10;
    int start = lid * C;
    int lsum = 0;
    for (int i = 0; i < C; ++i) {
        int idx = start + i;
        if (idx < n_nodes) lsum += (deg[idx] + 1) & ~1;
    }
    int x = lsum;                              // wave inclusive scan
    #pragma unroll
    for (int off = 1; off < 64; off <<= 1) {
        int y = __shfl_up(x, off);
        if (lane >= off) x += y;
    }
    if (lane == 63) wsum[wv] = x;
    __syncthreads();
    if (wv == 0 && lane < 16) {
        int t = wsum[lane];
        #pragma unroll
        for (int off = 1; off < 16; off <<= 1) {
            int y = __shfl_up(t, off);
            if (lane >= off) t += y;
        }
        wsum[lane] = t;
    }
    __syncthreads();
    int wbase = (wv > 0) ? wsum[wv - 1] : 0;
    int run = wbase + x - lsum;                // exclusive prefix for this thread
    for (int i = 0; i < C; ++i) {
        int idx = start + i;
        if (idx < n_nodes) { row_ptr[idx] = run; run += (deg[idx] + 1) & ~1; }
    }
}

// Fill: CSR edge ids AND src_csr directly (coalesced edge_src read).
__global__ void fill_kernel(const int* __restrict__ edge_dst, const int* __restrict__ edge_src,
                            const int* __restrict__ row_ptr,
                            int* __restrict__ fillc, int* __restrict__ eid,
                            int* __restrict__ src_csr, int n_edges) {
    for (int e = blockIdx.x*blockDim.x + threadIdx.x; e < n_edges; e += gridDim.x*blockDim.x) {
        int d = edge_dst[e];
        int s = edge_src[e];
        int ofs = atomicAdd(&fillc[d], 1);
        int slot = row_ptr[d] + ofs;
        eid[slot] = e;
        src_csr[slot] = s;
    }
}

// Fused: Cb (CSR order) + embed + iter-0 [A|B]. Also initializes out[].
// edgeconst: UNSWAPPED operands (A=edges, B=W3) -- lane stores 16x 2-B contiguous
// per tile (1-2 cache lines/instr); the swapped variant touched 16 lines/instr (r11 -5us).
__global__ __launch_bounds__(256) void edge_embed_kernel(
        const int* __restrict__ eid,
        const float* __restrict__ edge_data, const unsigned short* __restrict__ W3T,
        unsigned short* __restrict__ Cb, int Lmax, int ecblocks,
        const float* __restrict__ node_data, const unsigned short* __restrict__ WeT,
        const float* __restrict__ b_embed, unsigned short* __restrict__ hb,
        const unsigned short* __restrict__ WabT, const float* __restrict__ b_msg,
        unsigned short* __restrict__ Ab, unsigned short* __restrict__ Bb,
        float* __restrict__ out, const float* __restrict__ b_r2, int n_nodes) {
    __shared__ unsigned short hs[16 * 68];
    floatx4 z4 = {0.f,0.f,0.f,0.f};
    int lane = threadIdx.x & 63;
    int quad = lane >> 4, l16 = lane & 15;
    if ((int)blockIdx.x < ecblocks) {
        int w = blockIdx.x * 4 + (threadIdx.x >> 6);
        int e0 = w * 16;
        if (e0 >= Lmax) return;
        int erow = e0 + l16;
        int ev = eid[erow];                  // coalesced; 0 for pads
        short8 a0 = {0,0,0,0,0,0,0,0};       // k = quad*8..+8; real only k<16
        if (quad < 2) {
            const float4* ep = (const float4*)(edge_data + (size_t)ev*ED + quad*8);
            float4 x0 = ep[0], x1 = ep[1];
            a0[0]=(short)f2bf(x0.x); a0[1]=(short)f2bf(x0.y); a0[2]=(short)f2bf(x0.z); a0[3]=(short)f2bf(x0.w);
            a0[4]=(short)f2bf(x1.x); a0[5]=(short)f2bf(x1.y); a0[6]=(short)f2bf(x1.z); a0[7]=(short)f2bf(x1.w);
        }
        #pragma unroll
        for (int nt = 0; nt < 4; ++nt) {
            int n = nt*16 + l16;
            short8 b0 = *(const short8*)(W3T + (size_t)n*32 + quad*8);
            floatx4 d = __builtin_amdgcn_mfma_f32_16x16x32_bf16(a0, b0, z4, 0, 0, 0);
            #pragma unroll
            for (int r = 0; r < 4; ++r) {
                int e = e0 + quad*4 + r;
                Cb[(size_t)e*SD + n] = f2bf(d[r]);
            }
        }
    } else {
        int jt = threadIdx.x >> 6;
        int m0 = ((int)blockIdx.x - ecblocks) * 16;
        if (m0 >= n_nodes) return;
        if (m0 == 0 && threadIdx.x < RD)     // init readout accumulator (pre-gru ordering)
            out[threadIdx.x] = (float)n_nodes * b_r2[threadIdx.x];
        int mrow = m0 + l16; if (mrow >= n_nodes) mrow = n_nodes - 1;
        short8 a0 = {0,0,0,0,0,0,0,0};
        if (quad < 2) {
            const float4* np = (const float4*)(node_data + (size_t)mrow*VD + quad*8);
            float4 x0 = np[0], x1 = np[1];
            a0[0]=(short)f2bf(x0.x); a0[1]=(short)f2bf(x0.y); a0[2]=(short)f2bf(x0.z); a0[3]=(short)f2bf(x0.w);
            a0[4]=(short)f2bf(x1.x); a0[5]=(short)f2bf(x1.y); a0[6]=(short)f2bf(x1.z); a0[7]=(short)f2bf(x1.w);
        }
        int j = jt*16 + l16;
        short8 b0 = *(const short8*)(WeT + (size_t)j*32 + quad*8);
        floatx4 d = __builtin_amdgcn_mfma_f32_16x16x32_bf16(a0, b0, z4, 0, 0, 0);
        float bias = b_embed[j];
        #pragma unroll
        for (int r = 0; r < 4; ++r) {
            int m = m0 + quad*4 + r;
            unsigned short v16 = f2bf(d[r] + bias);
            hs[(quad*4 + r)*68 + j] = v16;
            if (m < n_nodes) hb[(size_t)m*SD + j] = v16;
        }
        __syncthreads();
        short8 aa0 = *(const short8*)(hs + l16*68 + quad*8);
        short8 aa1 = *(const short8*)(hs + l16*68 + 32 + quad*8);
        #pragma unroll
        for (int s = 0; s < 2; ++s) {
            int ncol = (jt + 4*s)*16 + l16;
            const short8* bp = (const short8*)(WabT + (size_t)ncol*SD + quad*8);
            floatx4 dd = __builtin_amdgcn_mfma_f32_16x16x32_bf16(aa0, bp[0], z4, 0, 0, 0);
            dd = __builtin_amdgcn_mfma_f32_16x16x32_bf16(aa1, bp[4], dd, 0, 0, 0);
            float bias2 = (s == 0) ? b_msg[ncol] : 0.f;
            int jc = jt*16 + l16;
            #pragma unroll
            for (int r = 0; r < 4; ++r) {
                int m = m0 + quad*4 + r;
                if (m >= n_nodes) break;
                float v = dd[r] + bias2;
                if (s == 0) Ab[(size_t)m*SD + jc] = f2bf(v);
                else        Bb[(size_t)m*SD + jc] = f2bf(v);
            }
        }
    }
}

// Aggregation: ONE NODE PER WAVE (round-8 verified form).
// Quarter-split: 4 groups of 16 lanes; lane owns 4 cols (8 B); one dwordx2 serves 4 edges.
// Pad reads in-bounds by construction; cnt guard keeps the sum exact.
template<int FIRST>
__global__ __launch_bounds__(256) void agg_kernel(
        const unsigned short* __restrict__ Abr, const unsigned short* __restrict__ Bbr,
        const unsigned short* __restrict__ Cb, const int* __restrict__ src_csr,
        const int* __restrict__ row_ptr, const int* __restrict__ deg,
        unsigned short* __restrict__ m_accb, int n_nodes) {
    int w = threadIdx.x >> 6, lane = threadIdx.x & 63;
    int n = blockIdx.x * 4 + w;
    if (n >= n_nodes) return;
    int q = lane >> 4, l16 = lane & 15, j4 = l16 * 4;
    int e0 = row_ptr[n], d = deg[n];
    uint2 a2 = *(const uint2*)(Abr + (size_t)n*SD + j4);
    float av0 = bflo(a2.x), av1 = bfhi(a2.x), av2 = bflo(a2.y), av3 = bfhi(a2.y);
    float b0 = 0.f, b1 = 0.f, b2 = 0.f, b3 = 0.f;
    if (!FIRST) {
        uint2 p2 = *(const uint2*)(m_accb + (size_t)n*SD + j4);
        b0 = bflo(p2.x); b1 = bfhi(p2.x); b2 = bflo(p2.y); b3 = bfhi(p2.y);
    }
    float acc0 = 0.f, acc1 = 0.f, acc2 = 0.f, acc3 = 0.f;
    for (int c = 0; c*16 < d; ++c) {
        int i = e0 + c*16 + l16;
        int sv = src_csr[i];
        int cnt = d - c*16;
        #pragma unroll
        for (int p = 0; p < 4; ++p) {
            int s0 = __builtin_amdgcn_readlane(sv, 4*p+0);
            int s1 = __builtin_amdgcn_readlane(sv, 4*p+1);
            int s2 = __builtin_amdgcn_readlane(sv, 4*p+2);
            int s3 = __builtin_amdgcn_readlane(sv, 4*p+3);
            int t0 = (q & 1) ? s1 : s0;
            int t1 = (q & 1) ? s3 : s2;
            int s  = (q & 2) ? t1 : t0;
            uint2 bu = *(const uint2*)(Bbr + (size_t)s*SD + j4);
            int et = e0 + c*16 + 4*p + q;
            uint2 cu = *(const uint2*)(Cb + (size_t)et*SD + j4);
            if (4*p + q < cnt) {
                acc0 += fmaxf(av0 + bflo(bu.x) + bflo(cu.x), 0.f);
                acc1 += fmaxf(av1 + bfhi(bu.x) + bfhi(cu.x), 0.f);
                acc2 += fmaxf(av2 + bflo(bu.y) + bflo(cu.y), 0.f);
                acc3 += fmaxf(av3 + bfhi(bu.y) + bfhi(cu.y), 0.f);
            }
        }
    }
    acc0 += __shfl_xor(acc0, 16); acc0 += __shfl_xor(acc0, 32);
    acc1 += __shfl_xor(acc1, 16); acc1 += __shfl_xor(acc1, 32);
    acc2 += __shfl_xor(acc2, 16); acc2 += __shfl_xor(acc2, 32);
    acc3 += __shfl_xor(acc3, 16); acc3 += __shfl_xor(acc3, 32);
    unsigned pk0 = (unsigned)f2bf(b0 + acc0) | (((unsigned)f2bf(b1 + acc1)) << 16);
    unsigned pk1 = (unsigned)f2bf(b2 + acc2) | (((unsigned)f2bf(b3 + acc3)) << 16);
    if (q == 0)
        *(uint2*)(m_accb + (size_t)n*SD + j4) = make_uint2(pk0, pk1);
}

// GRU + next-[A|B] (or readout into out[] via atomics). Block = 16-node tile, 4 waves.
template<int LAST>
__global__ __launch_bounds__(256) void gru_kernel(
        const unsigned short* __restrict__ hbr, unsigned short* __restrict__ hbw,
        const unsigned short* __restrict__ m_accb,
        unsigned short* __restrict__ Abw, unsigned short* __restrict__ Bbw,
        const unsigned short* __restrict__ WiT, const unsigned short* __restrict__ WhT,
        const float* __restrict__ b_i, const float* __restrict__ b_h,
        const unsigned short* __restrict__ WabT, const float* __restrict__ b_msg,
        const float* __restrict__ W_r1, const float* __restrict__ b_r1,
        const float* __restrict__ W_r2, float* __restrict__ out,
        int n_nodes) {
    __shared__ unsigned short hsn[16 * 68];   // hnew tile (bf16)
    int w = threadIdx.x >> 6, lane = threadIdx.x & 63;
    int m0 = blockIdx.x * 16;
    if (m0 >= n_nodes) return;
    int quad = lane >> 4, l16 = lane & 15;
    int mrow = m0 + l16; if (mrow >= n_nodes) mrow = n_nodes - 1;
    const short8* mp = (const short8*)(m_accb + (size_t)mrow*SD + quad*8);
    short8 ma0 = mp[0], ma1 = mp[4];
    const short8* hp = (const short8*)(hbr + (size_t)mrow*SD + quad*8);
    short8 ha0 = hp[0], ha1 = hp[4];
    int j0 = w * 16;
    floatx4 di[3], dh[3];
    floatx4 z4 = {0.f,0.f,0.f,0.f};
    #pragma unroll
    for (int g = 0; g < 3; ++g) {
        int n = g*64 + j0 + l16;
        const short8* bi = (const short8*)(WiT + (size_t)n*SD + quad*8);
        const short8* bh = (const short8*)(WhT + (size_t)n*SD + quad*8);
        di[g] = __builtin_amdgcn_mfma_f32_16x16x32_bf16(ma0, bi[0], z4,    0, 0, 0);
        di[g] = __builtin_amdgcn_mfma_f32_16x16x32_bf16(ma1, bi[4], di[g], 0, 0, 0);
        dh[g] = __builtin_amdgcn_mfma_f32_16x16x32_bf16(ha0, bh[0], z4,    0, 0, 0);
        dh[g] = __builtin_amdgcn_mfma_f32_16x16x32_bf16(ha1, bh[4], dh[g], 0, 0, 0);
    }
    int j = j0 + l16;
    float bir = b_i[j], biz = b_i[64+j], bin = b_i[128+j];
    float bhr = b_h[j], bhz = b_h[64+j], bhn = b_h[128+j];
    #pragma unroll
    for (int r = 0; r < 4; ++r) {
        int m = m0 + quad*4 + r;
        int mc = m < n_nodes ? m : n_nodes - 1;
        float rg = sigmoid_f(di[0][r] + bir + dh[0][r] + bhr);
        float zg = sigmoid_f(di[1][r] + biz + dh[1][r] + bhz);
        float ng = tanh_f(di[2][r] + bin + rg * (dh[2][r] + bhn));
        float hold = bf2f(hbr[(size_t)mc*SD + j]);
        float hnew = (1.f - zg) * ng + zg * hold;
        unsigned short hb16 = f2bf(hnew);
        hsn[(quad*4 + r)*68 + j] = hb16;
        if (!LAST && m < n_nodes) hbw[(size_t)m*SD + j] = hb16;
    }

    if (!LAST) {
        // ---- next iteration's [A|B] ----
        __syncthreads();
        short8 a0 = *(const short8*)(hsn + l16*68 + quad*8);
        short8 a1 = *(const short8*)(hsn + l16*68 + 32 + quad*8);
        #pragma unroll
        for (int s = 0; s < 2; ++s) {
            int ncol = (w + 4*s)*16 + l16;
            const short8* bp = (const short8*)(WabT + (size_t)ncol*SD + quad*8);
            floatx4 d = __builtin_amdgcn_mfma_f32_16x16x32_bf16(a0, bp[0], z4, 0, 0, 0);
            d = __builtin_amdgcn_mfma_f32_16x16x32_bf16(a1, bp[4], d, 0, 0, 0);
            float bias = (s == 0) ? b_msg[ncol] : 0.f;
            int jc = w*16 + l16;
            #pragma unroll
            for (int r = 0; r < 4; ++r) {
                int m = m0 + quad*4 + r;
                if (m >= n_nodes) break;
                float v = d[r] + bias;
                if (s == 0) Abw[(size_t)m*SD + jc] = f2bf(v);
                else        Bbw[(size_t)m*SD + jc] = f2bf(v);
            }
        }
    } else {
        // ---- fused readout, accumulated straight into out[] ----
        __syncthreads();
        __shared__ float ts[16 * 12];        // hidden, padded stride
        __shared__ float po[512];
        int tid = threadIdx.x;
        if (tid < 16 * RH) {
            int node = tid / RH, i = tid - node * RH;
            float a = b_r1[i];
            #pragma unroll 8
            for (int k = 0; k < SD; ++k)
                a += bf2f(hsn[node*68 + k]) * W_r1[k*RH + i];
            ts[node*12 + i] = fmaxf(a, 0.f);
        }
        __syncthreads();
        #pragma unroll
        for (int s = 0; s < 2; ++s) {
            int task = tid + s*256;          // (node, c)
            int node = task >> 5, c = task & 31;
            float v = 0.f;
            if (m0 + node < n_nodes) {
                #pragma unroll
                for (int i = 0; i < RH; ++i) v += ts[node*12 + i] * W_r2[i*RD + c];
            }
            po[task] = v;
        }
        __syncthreads();
        if (tid < RD) {
            float s2 = 0.f;
            #pragma unroll
            for (int n = 0; n < 16; ++n) s2 += po[n*32 + tid];
            atomicAdd(&out[tid], s2);
        }
    }
}

extern "C" void kernel_launch(void* const* d_in, const int* in_sizes, int n_in,
                              void* d_out, int out_size, void* d_ws, size_t ws_size,
                              hipStream_t stream) {
    const float* node_data = (const float*)d_in[0];
    const float* edge_data = (const float*)d_in[1];
    const int*   edge_src  = (const int*)d_in[2];
    const int*   edge_dst  = (const int*)d_in[3];
    const float* W_embed   = (const float*)d_in[4];
    const float* b_embed   = (const float*)d_in[5];
    const float* W_msg     = (const float*)d_in[6];
    const float* b_msg     = (const float*)d_in[7];
    const float* W_i       = (const float*)d_in[8];
    const float* b_i       = (const float*)d_in[9];
    const float* W_h       = (const float*)d_in[10];
    const float* b_h       = (const float*)d_in[11];
    const float* W_r1      = (const float*)d_in[12];
    const float* b_r1      = (const float*)d_in[13];
    const float* W_r2      = (const float*)d_in[14];
    const float* b_r2      = (const float*)d_in[15];

    int n_nodes = in_sizes[0] / VD;    // 20000
    int n_edges = in_sizes[2];         // 320000
    int Lmax = n_edges + n_nodes + 64; // padded CSR capacity
    int mtiles16 = (n_nodes + 15) / 16;
    int ntiles4  = (n_nodes + 3) / 4;  // agg blocks (4 node-waves each)

    char* ws = (char*)d_ws;
    size_t off = 0;
    auto alloc = [&](size_t bytes) {
        void* p = ws + off;
        off = (off + bytes + 255) & ~(size_t)255;
        return p;
    };
    unsigned short* m_accb = (unsigned short*)alloc((size_t)n_nodes * SD * 2);
    unsigned short* hbA = (unsigned short*)alloc((size_t)n_nodes * SD * 2);
    unsigned short* hbB = (unsigned short*)alloc((size_t)n_nodes * SD * 2);
    unsigned short* Ab0 = (unsigned short*)alloc((size_t)n_nodes * SD * 2);
    unsigned short* Bb0 = (unsigned short*)alloc((size_t)n_nodes * SD * 2);
    unsigned short* Ab1 = (unsigned short*)alloc((size_t)n_nodes * SD * 2);
    unsigned short* Bb1 = (unsigned short*)alloc((size_t)n_nodes * SD * 2);
    unsigned short* Cb  = (unsigned short*)alloc((size_t)(Lmax + 32) * SD * 2);
    int*   row_ptr      = (int*)alloc((size_t)(n_nodes + 1) * sizeof(int));
    // contiguous zero-init region: deg, fillc, eid, src_csr (one memset)
    char*  zbase        = (char*)alloc(0);
    int*   deg          = (int*)alloc((size_t)n_nodes * sizeof(int));
    int*   fillc        = (int*)alloc((size_t)n_nodes * sizeof(int));
    int*   eid          = (int*)alloc((size_t)(Lmax + 32) * sizeof(int));
    int*   src_csr      = (int*)alloc((size_t)(Lmax + 32) * sizeof(int));
    char*  zend         = (char*)alloc(0);
    unsigned short* WabT = (unsigned short*)alloc(128*64*2);
    unsigned short* WiT  = (unsigned short*)alloc(192*64*2);
    unsigned short* WhT  = (unsigned short*)alloc(192*64*2);
    unsigned short* W3T  = (unsigned short*)alloc(64*32*2);
    unsigned short* WeT  = (unsigned short*)alloc(64*32*2);
    (void)ws_size; (void)n_in;

    hipMemsetAsync(zbase, 0, (size_t)(zend - zbase), stream);

    prep_hist_kernel<<<96 + (n_edges + 255)/256, 256, 0, stream>>>(
        W_msg, W_i, W_h, W_embed, WabT, WiT, WhT, W3T, WeT, edge_dst, deg, n_edges);

    scan_kernel<<<1, 1024, 0, stream>>>(deg, row_ptr, n_nodes);

    fill_kernel<<<(n_edges + 255)/256, 256, 0, stream>>>(edge_dst, edge_src, row_ptr,
                                                         fillc, eid, src_csr, n_edges);

    int ecblocks = ((Lmax + 15)/16 + 3) / 4;
    edge_embed_kernel<<<ecblocks + mtiles16, 256, 0, stream>>>(
        eid, edge_data, W3T, Cb, Lmax, ecblocks,
        node_data, WeT, b_embed, hbA, WabT, b_msg, Ab0, Bb0,
        (float*)d_out, b_r2, n_nodes);

    // it0
    agg_kernel<1><<<ntiles4, 256, 0, stream>>>(Ab0, Bb0, Cb, src_csr, row_ptr, deg,
                                               m_accb, n_nodes);
    gru_kernel<0><<<mtiles16, 256, 0, stream>>>(hbA, hbB, m_accb, Ab1, Bb1,
        WiT, WhT, b_i, b_h, WabT, b_msg, W_r1, b_r1, W_r2, (float*)d_out, n_nodes);
    // it1
    agg_kernel<0><<<ntiles4, 256, 0, stream>>>(Ab1, Bb1, Cb, src_csr, row_ptr, deg,
                                               m_accb, n_nodes);
    gru_kernel<0><<<mtiles16, 256, 0, stream>>>(hbB, hbA, m_accb, Ab0, Bb0,
        WiT, WhT, b_i, b_h, WabT, b_msg, W_r1, b_r1, W_r2, (float*)d_out, n_nodes);
    // it2 (LAST)
    agg_kernel<0><<<ntiles4, 256, 0, stream>>>(Ab0, Bb0, Cb, src_csr, row_ptr, deg,
                                               m_accb, n_nodes);
    gru_kernel<1><<<mtiles16, 256, 0, stream>>>(hbA, hbB, m_accb, Ab1, Bb1,
        WiT, WhT, b_i, b_h, WabT, b_msg, W_r1, b_r1, W_r2, (float*)d_out, n_nodes);
}

// Round 13
// 274.155 us; speedup vs baseline: 1.0829x; 1.0829x over previous
//
#include <hip/hip_runtime.h>

static constexpr int VD = 16;     // vertex feature dim
static constexpr int SD = 64;     // state dim
static constexpr int ED = 16;     // edge feature dim
static constexpr int RH = 10, RD = 32;
static constexpr int N_ITERS = 3;

typedef __attribute__((ext_vector_type(8))) short short8;
typedef __attribute__((ext_vector_type(4))) float floatx4;

__device__ __forceinline__ float sigmoid_f(float x) {
    return 1.f / (1.f + __expf(-x));
}
__device__ __forceinline__ float tanh_f(float x) {
    x = fminf(fmaxf(x, -20.f), 20.f);
    float e = __expf(2.f * x);
    return (e - 1.f) / (e + 1.f);
}
__device__ __forceinline__ unsigned short f2bf(float x) {   // round-to-nearest-even
    unsigned u = __float_as_uint(x);
    unsigned r = (u + 0x7FFFu + ((u >> 16) & 1u)) >> 16;
    return (unsigned short)r;
}
__device__ __forceinline__ float bf2f(unsigned short s) {
    return __uint_as_float(((unsigned)s) << 16);
}
__device__ __forceinline__ float bflo(unsigned u) { return __uint_as_float(u << 16); }
__device__ __forceinline__ float bfhi(unsigned u) { return __uint_as_float(u & 0xFFFF0000u); }

// Fused: one-time bf16 weight transposes (blocks 0..95) + degree histogram (blocks 96..).
__global__ void prep_hist_kernel(const float* __restrict__ W_msg,
                                 const float* __restrict__ W_i, const float* __restrict__ W_h,
                                 const float* __restrict__ W_embed,
                                 unsigned short* __restrict__ WabT, unsigned short* __restrict__ WiT,
                                 unsigned short* __restrict__ WhT, unsigned short* __restrict__ W3T,
                                 unsigned short* __restrict__ WeT,
                                 const int* __restrict__ edge_dst, int* __restrict__ deg,
                                 int n_edges) {
    if ((int)blockIdx.x < 96) {              // 96*256 = 24576 = total weight elems
        int i = blockIdx.x * 256 + threadIdx.x;
        if (i < 128*64) {                    // WabT[n][k]: n<64 -> W1 col n; else W2 col n-64
            int n = i >> 6, k = i & 63;
            WabT[i] = f2bf(W_msg[((n < 64 ? 0 : 64) + k)*64 + (n & 63)]);
        }
        int j = i - 128*64;
        if (j >= 0 && j < 192*64) {          // WiT/WhT[n][k] = W[k][n]
            int n = j >> 6, k = j & 63;
            WiT[j] = f2bf(W_i[k*192 + n]);
            WhT[j] = f2bf(W_h[k*192 + n]);
        }
        int l = i - 128*64 - 192*64;
        if (l >= 0 && l < 64*32) {           // W3T[n][k], k padded 16->32 with zeros
            int n = l >> 5, k = l & 31;
            W3T[l] = (k < 16) ? f2bf(W_msg[(128+k)*64 + n]) : (unsigned short)0;
        }
        int m = i - 128*64 - 192*64 - 64*32;
        if (m >= 0 && m < 64*32) {           // WeT[n][k], k padded 16->32 (embed)
            int n = m >> 5, k = m & 31;
            WeT[m] = (k < 16) ? f2bf(W_embed[k*64 + n]) : (unsigned short)0;
        }
    } else {
        int e = ((int)blockIdx.x - 96) * 256 + threadIdx.x;
        if (e < n_edges) atomicAdd(&deg[edge_dst[e]], 1);
    }
}

// Multi-block exclusive scan of EVEN-PADDED degrees -> row_ptr. 1024 nodes/block.
// (Measured: the single-block 1024-thread scan costs ~25 us (r12, 296.9 vs 274.4);
//  three tiny dispatches at ~2-3 us each are far cheaper.)
__global__ __launch_bounds__(256) void scan1_kernel(const int* __restrict__ deg,
                                                    int* __restrict__ bsum, int n_nodes) {
    __shared__ int ws[4];
    int tid = threadIdx.x, lane = tid & 63, wv = tid >> 6;
    int base = blockIdx.x * 1024 + tid * 4;
    int s = 0;
    #pragma unroll
    for (int i = 0; i < 4; ++i) {
        int idx = base + i;
        if (idx < n_nodes) s += (deg[idx] + 1) & ~1;
    }
    #pragma unroll
    for (int off = 1; off < 64; off <<= 1) s += __shfl_xor(s, off);
    if (lane == 0) ws[wv] = s;
    __syncthreads();
    if (tid == 0) bsum[blockIdx.x] = ws[0] + ws[1] + ws[2] + ws[3];
}

__global__ __launch_bounds__(64) void scan2_kernel(int* __restrict__ bsum, int nb) {
    int lane = threadIdx.x;
    int v = (lane < nb) ? bsum[lane] : 0;
    int x = v;
    #pragma unroll
    for (int off = 1; off < 64; off <<= 1) {
        int y = __shfl_up(x, off);
        if (lane >= off) x += y;
    }
    if (lane < nb) bsum[lane] = x - v;       // exclusive
}

__global__ __launch_bounds__(256) void scan3_kernel(const int* __restrict__ deg,
                                                    const int* __restrict__ bsum,
                                                    int* __restrict__ row_ptr, int n_nodes) {
    __shared__ int ws[4];
    int tid = threadIdx.x, lane = tid & 63, wv = tid >> 6;
    int base = blockIdx.x * 1024 + tid * 4;
    int d[4], ts = 0;
    #pragma unroll
    for (int i = 0; i < 4; ++i) {
        int idx = base + i;
        d[i] = (idx < n_nodes) ? ((deg[idx] + 1) & ~1) : 0;
        ts += d[i];
    }
    int x = ts;
    #pragma unroll
    for (int off = 1; off < 64; off <<= 1) {
        int y = __shfl_up(x, off);
        if (lane >= off) x += y;
    }
    if (lane == 63) ws[wv] = x;
    __syncthreads();
    int wo = 0;
    #pragma unroll
    for (int k = 0; k < 4; ++k) if (k < wv) wo += ws[k];
    int run = bsum[blockIdx.x] + wo + (x - ts);
    #pragma unroll
    for (int i = 0; i < 4; ++i) {
        int idx = base + i;
        if (idx < n_nodes) row_ptr[idx] = run;
        run += d[i];
    }
}

// Fill: CSR edge ids AND src_csr directly (coalesced edge_src read).
__global__ void fill_kernel(const int* __restrict__ edge_dst, const int* __restrict__ edge_src,
                            const int* __restrict__ row_ptr,
                            int* __restrict__ fillc, int* __restrict__ eid,
                            int* __restrict__ src_csr, int n_edges) {
    for (int e = blockIdx.x*blockDim.x + threadIdx.x; e < n_edges; e += gridDim.x*blockDim.x) {
        int d = edge_dst[e];
        int s = edge_src[e];
        int ofs = atomicAdd(&fillc[d], 1);
        int slot = row_ptr[d] + ofs;
        eid[slot] = e;
        src_csr[slot] = s;
    }
}

// Fused: Cb (CSR order) + embed + iter-0 [A|B]. Also initializes out[].
// edgeconst: UNSWAPPED operands (A=edges, B=W3) -- 16 lanes store 2-B contiguous
// (1-2 cache lines/instr); the swapped variant touched 16 lines/instr (r11, -5us).
__global__ __launch_bounds__(256) void edge_embed_kernel(
        const int* __restrict__ eid,
        const float* __restrict__ edge_data, const unsigned short* __restrict__ W3T,
        unsigned short* __restrict__ Cb, int Lmax, int ecblocks,
        const float* __restrict__ node_data, const unsigned short* __restrict__ WeT,
        const float* __restrict__ b_embed, unsigned short* __restrict__ hb,
        const unsigned short* __restrict__ WabT, const float* __restrict__ b_msg,
        unsigned short* __restrict__ Ab, unsigned short* __restrict__ Bb,
        float* __restrict__ out, const float* __restrict__ b_r2, int n_nodes) {
    __shared__ unsigned short hs[16 * 68];
    floatx4 z4 = {0.f,0.f,0.f,0.f};
    int lane = threadIdx.x & 63;
    int quad = lane >> 4, l16 = lane & 15;
    if ((int)blockIdx.x < ecblocks) {
        int w = blockIdx.x * 4 + (threadIdx.x >> 6);
        int e0 = w * 16;
        if (e0 >= Lmax) return;
        int erow = e0 + l16;
        int ev = eid[erow];                  // coalesced; 0 for pads
        short8 a0 = {0,0,0,0,0,0,0,0};       // k = quad*8..+8; real only k<16
        if (quad < 2) {
            const float4* ep = (const float4*)(edge_data + (size_t)ev*ED + quad*8);
            float4 x0 = ep[0], x1 = ep[1];
            a0[0]=(short)f2bf(x0.x); a0[1]=(short)f2bf(x0.y); a0[2]=(short)f2bf(x0.z); a0[3]=(short)f2bf(x0.w);
            a0[4]=(short)f2bf(x1.x); a0[5]=(short)f2bf(x1.y); a0[6]=(short)f2bf(x1.z); a0[7]=(short)f2bf(x1.w);
        }
        #pragma unroll
        for (int nt = 0; nt < 4; ++nt) {
            int n = nt*16 + l16;
            short8 b0 = *(const short8*)(W3T + (size_t)n*32 + quad*8);
            floatx4 d = __builtin_amdgcn_mfma_f32_16x16x32_bf16(a0, b0, z4, 0, 0, 0);
            #pragma unroll
            for (int r = 0; r < 4; ++r) {
                int e = e0 + quad*4 + r;
                Cb[(size_t)e*SD + n] = f2bf(d[r]);
            }
        }
    } else {
        int jt = threadIdx.x >> 6;
        int m0 = ((int)blockIdx.x - ecblocks) * 16;
        if (m0 >= n_nodes) return;
        if (m0 == 0 && threadIdx.x < RD)     // init readout accumulator (pre-gru ordering)
            out[threadIdx.x] = (float)n_nodes * b_r2[threadIdx.x];
        int mrow = m0 + l16; if (mrow >= n_nodes) mrow = n_nodes - 1;
        short8 a0 = {0,0,0,0,0,0,0,0};
        if (quad < 2) {
            const float4* np = (const float4*)(node_data + (size_t)mrow*VD + quad*8);
            float4 x0 = np[0], x1 = np[1];
            a0[0]=(short)f2bf(x0.x); a0[1]=(short)f2bf(x0.y); a0[2]=(short)f2bf(x0.z); a0[3]=(short)f2bf(x0.w);
            a0[4]=(short)f2bf(x1.x); a0[5]=(short)f2bf(x1.y); a0[6]=(short)f2bf(x1.z); a0[7]=(short)f2bf(x1.w);
        }
        int j = jt*16 + l16;
        short8 b0 = *(const short8*)(WeT + (size_t)j*32 + quad*8);
        floatx4 d = __builtin_amdgcn_mfma_f32_16x16x32_bf16(a0, b0, z4, 0, 0, 0);
        float bias = b_embed[j];
        #pragma unroll
        for (int r = 0; r < 4; ++r) {
            int m = m0 + quad*4 + r;
            unsigned short v16 = f2bf(d[r] + bias);
            hs[(quad*4 + r)*68 + j] = v16;
            if (m < n_nodes) hb[(size_t)m*SD + j] = v16;
        }
        __syncthreads();
        short8 aa0 = *(const short8*)(hs + l16*68 + quad*8);
        short8 aa1 = *(const short8*)(hs + l16*68 + 32 + quad*8);
        #pragma unroll
        for (int s = 0; s < 2; ++s) {
            int ncol = (jt + 4*s)*16 + l16;
            const short8* bp = (const short8*)(WabT + (size_t)ncol*SD + quad*8);
            floatx4 dd = __builtin_amdgcn_mfma_f32_16x16x32_bf16(aa0, bp[0], z4, 0, 0, 0);
            dd = __builtin_amdgcn_mfma_f32_16x16x32_bf16(aa1, bp[4], dd, 0, 0, 0);
            float bias2 = (s == 0) ? b_msg[ncol] : 0.f;
            int jc = jt*16 + l16;
            #pragma unroll
            for (int r = 0; r < 4; ++r) {
                int m = m0 + quad*4 + r;
                if (m >= n_nodes) break;
                float v = dd[r] + bias2;
                if (s == 0) Ab[(size_t)m*SD + jc] = f2bf(v);
                else        Bb[(size_t)m*SD + jc] = f2bf(v);
            }
        }
    }
}

// Aggregation: ONE NODE PER WAVE (round-8 verified form).
// Quarter-split: 4 groups of 16 lanes; lane owns 4 cols (8 B); one dwordx2 serves 4 edges.
// Pad reads in-bounds by construction; cnt guard keeps the sum exact.
template<int FIRST>
__global__ __launch_bounds__(256) void agg_kernel(
        const unsigned short* __restrict__ Abr, const unsigned short* __restrict__ Bbr,
        const unsigned short* __restrict__ Cb, const int* __restrict__ src_csr,
        const int* __restrict__ row_ptr, const int* __restrict__ deg,
        unsigned short* __restrict__ m_accb, int n_nodes) {
    int w = threadIdx.x >> 6, lane = threadIdx.x & 63;
    int n = blockIdx.x * 4 + w;
    if (n >= n_nodes) return;
    int q = lane >> 4, l16 = lane & 15, j4 = l16 * 4;
    int e0 = row_ptr[n], d = deg[n];
    uint2 a2 = *(const uint2*)(Abr + (size_t)n*SD + j4);
    float av0 = bflo(a2.x), av1 = bfhi(a2.x), av2 = bflo(a2.y), av3 = bfhi(a2.y);
    float b0 = 0.f, b1 = 0.f, b2 = 0.f, b3 = 0.f;
    if (!FIRST) {
        uint2 p2 = *(const uint2*)(m_accb + (size_t)n*SD + j4);
        b0 = bflo(p2.x); b1 = bfhi(p2.x); b2 = bflo(p2.y); b3 = bfhi(p2.y);
    }
    float acc0 = 0.f, acc1 = 0.f, acc2 = 0.f, acc3 = 0.f;
    for (int c = 0; c*16 < d; ++c) {
        int i = e0 + c*16 + l16;
        int sv = src_csr[i];
        int cnt = d - c*16;
        #pragma unroll
        for (int p = 0; p < 4; ++p) {
            int s0 = __builtin_amdgcn_readlane(sv, 4*p+0);
            int s1 = __builtin_amdgcn_readlane(sv, 4*p+1);
            int s2 = __builtin_amdgcn_readlane(sv, 4*p+2);
            int s3 = __builtin_amdgcn_readlane(sv, 4*p+3);
            int t0 = (q & 1) ? s1 : s0;
            int t1 = (q & 1) ? s3 : s2;
            int s  = (q & 2) ? t1 : t0;
            uint2 bu = *(const uint2*)(Bbr + (size_t)s*SD + j4);
            int et = e0 + c*16 + 4*p + q;
            uint2 cu = *(const uint2*)(Cb + (size_t)et*SD + j4);
            if (4*p + q < cnt) {
                acc0 += fmaxf(av0 + bflo(bu.x) + bflo(cu.x), 0.f);
                acc1 += fmaxf(av1 + bfhi(bu.x) + bfhi(cu.x), 0.f);
                acc2 += fmaxf(av2 + bflo(bu.y) + bflo(cu.y), 0.f);
                acc3 += fmaxf(av3 + bfhi(bu.y) + bfhi(cu.y), 0.f);
            }
        }
    }
    acc0 += __shfl_xor(acc0, 16); acc0 += __shfl_xor(acc0, 32);
    acc1 += __shfl_xor(acc1, 16); acc1 += __shfl_xor(acc1, 32);
    acc2 += __shfl_xor(acc2, 16); acc2 += __shfl_xor(acc2, 32);
    acc3 += __shfl_xor(acc3, 16); acc3 += __shfl_xor(acc3, 32);
    unsigned pk0 = (unsigned)f2bf(b0 + acc0) | (((unsigned)f2bf(b1 + acc1)) << 16);
    unsigned pk1 = (unsigned)f2bf(b2 + acc2) | (((unsigned)f2bf(b3 + acc3)) << 16);
    if (q == 0)
        *(uint2*)(m_accb + (size_t)n*SD + j4) = make_uint2(pk0, pk1);
}

// GRU + next-[A|B] (or readout into out[] via atomics). Block = 16-node tile, 4 waves.
template<int LAST>
__global__ __launch_bounds__(256) void gru_kernel(
        const unsigned short* __restrict__ hbr, unsigned short* __restrict__ hbw,
        const unsigned short* __restrict__ m_accb,
        unsigned short* __restrict__ Abw, unsigned short* __restrict__ Bbw,
        const unsigned short* __restrict__ WiT, const unsigned short* __restrict__ WhT,
        const float* __restrict__ b_i, const float* __restrict__ b_h,
        const unsigned short* __restrict__ WabT, const float* __restrict__ b_msg,
        const float* __restrict__ W_r1, const float* __restrict__ b_r1,
        const float* __restrict__ W_r2, float* __restrict__ out,
        int n_nodes) {
    __shared__ unsigned short hsn[16 * 68];   // hnew tile (bf16)
    int w = threadIdx.x >> 6, lane = threadIdx.x & 63;
    int m0 = blockIdx.x * 16;
    if (m0 >= n_nodes) return;
    int quad = lane >> 4, l16 = lane & 15;
    int mrow = m0 + l16; if (mrow >= n_nodes) mrow = n_nodes - 1;
    const short8* mp = (const short8*)(m_accb + (size_t)mrow*SD + quad*8);
    short8 ma0 = mp[0], ma1 = mp[4];
    const short8* hp = (const short8*)(hbr + (size_t)mrow*SD + quad*8);
    short8 ha0 = hp[0], ha1 = hp[4];
    int j0 = w * 16;
    floatx4 di[3], dh[3];
    floatx4 z4 = {0.f,0.f,0.f,0.f};
    #pragma unroll
    for (int g = 0; g < 3; ++g) {
        int n = g*64 + j0 + l16;
        const short8* bi = (const short8*)(WiT + (size_t)n*SD + quad*8);
        const short8* bh = (const short8*)(WhT + (size_t)n*SD + quad*8);
        di[g] = __builtin_amdgcn_mfma_f32_16x16x32_bf16(ma0, bi[0], z4,    0, 0, 0);
        di[g] = __builtin_amdgcn_mfma_f32_16x16x32_bf16(ma1, bi[4], di[g], 0, 0, 0);
        dh[g] = __builtin_amdgcn_mfma_f32_16x16x32_bf16(ha0, bh[0], z4,    0, 0, 0);
        dh[g] = __builtin_amdgcn_mfma_f32_16x16x32_bf16(ha1, bh[4], dh[g], 0, 0, 0);
    }
    int j = j0 + l16;
    float bir = b_i[j], biz = b_i[64+j], bin = b_i[128+j];
    float bhr = b_h[j], bhz = b_h[64+j], bhn = b_h[128+j];
    #pragma unroll
    for (int r = 0; r < 4; ++r) {
        int m = m0 + quad*4 + r;
        int mc = m < n_nodes ? m : n_nodes - 1;
        float rg = sigmoid_f(di[0][r] + bir + dh[0][r] + bhr);
        float zg = sigmoid_f(di[1][r] + biz + dh[1][r] + bhz);
        float ng = tanh_f(di[2][r] + bin + rg * (dh[2][r] + bhn));
        float hold = bf2f(hbr[(size_t)mc*SD + j]);
        float hnew = (1.f - zg) * ng + zg * hold;
        unsigned short hb16 = f2bf(hnew);
        hsn[(quad*4 + r)*68 + j] = hb16;
        if (!LAST && m < n_nodes) hbw[(size_t)m*SD + j] = hb16;
    }

    if (!LAST) {
        // ---- next iteration's [A|B] ----
        __syncthreads();
        short8 a0 = *(const short8*)(hsn + l16*68 + quad*8);
        short8 a1 = *(const short8*)(hsn + l16*68 + 32 + quad*8);
        #pragma unroll
        for (int s = 0; s < 2; ++s) {
            int ncol = (w + 4*s)*16 + l16;
            const short8* bp = (const short8*)(WabT + (size_t)ncol*SD + quad*8);
            floatx4 d = __builtin_amdgcn_mfma_f32_16x16x32_bf16(a0, bp[0], z4, 0, 0, 0);
            d = __builtin_amdgcn_mfma_f32_16x16x32_bf16(a1, bp[4], d, 0, 0, 0);
            float bias = (s == 0) ? b_msg[ncol] : 0.f;
            int jc = w*16 + l16;
            #pragma unroll
            for (int r = 0; r < 4; ++r) {
                int m = m0 + quad*4 + r;
                if (m >= n_nodes) break;
                float v = d[r] + bias;
                if (s == 0) Abw[(size_t)m*SD + jc] = f2bf(v);
                else        Bbw[(size_t)m*SD + jc] = f2bf(v);
            }
        }
    } else {
        // ---- fused readout, accumulated straight into out[] ----
        __syncthreads();
        __shared__ float ts[16 * 12];        // hidden, padded stride
        __shared__ float po[512];
        int tid = threadIdx.x;
        if (tid < 16 * RH) {
            int node = tid / RH, i = tid - node * RH;
            float a = b_r1[i];
            #pragma unroll 8
            for (int k = 0; k < SD; ++k)
                a += bf2f(hsn[node*68 + k]) * W_r1[k*RH + i];
            ts[node*12 + i] = fmaxf(a, 0.f);
        }
        __syncthreads();
        #pragma unroll
        for (int s = 0; s < 2; ++s) {
            int task = tid + s*256;          // (node, c)
            int node = task >> 5, c = task & 31;
            float v = 0.f;
            if (m0 + node < n_nodes) {
                #pragma unroll
                for (int i = 0; i < RH; ++i) v += ts[node*12 + i] * W_r2[i*RD + c];
            }
            po[task] = v;
        }
        __syncthreads();
        if (tid < RD) {
            float s2 = 0.f;
            #pragma unroll
            for (int n = 0; n < 16; ++n) s2 += po[n*32 + tid];
            atomicAdd(&out[tid], s2);
        }
    }
}

extern "C" void kernel_launch(void* const* d_in, const int* in_sizes, int n_in,
                              void* d_out, int out_size, void* d_ws, size_t ws_size,
                              hipStream_t stream) {
    const float* node_data = (const float*)d_in[0];
    const float* edge_data = (const float*)d_in[1];
    const int*   edge_src  = (const int*)d_in[2];
    const int*   edge_dst  = (const int*)d_in[3];
    const float* W_embed   = (const float*)d_in[4];
    const float* b_embed   = (const float*)d_in[5];
    const float* W_msg     = (const float*)d_in[6];
    const float* b_msg     = (const float*)d_in[7];
    const float* W_i       = (const float*)d_in[8];
    const float* b_i       = (const float*)d_in[9];
    const float* W_h       = (const float*)d_in[10];
    const float* b_h       = (const float*)d_in[11];
    const float* W_r1      = (const float*)d_in[12];
    const float* b_r1      = (const float*)d_in[13];
    const float* W_r2      = (const float*)d_in[14];
    const float* b_r2      = (const float*)d_in[15];

    int n_nodes = in_sizes[0] / VD;    // 20000
    int n_edges = in_sizes[2];         // 320000
    int Lmax = n_edges + n_nodes + 64; // padded CSR capacity
    int mtiles16 = (n_nodes + 15) / 16;
    int ntiles4  = (n_nodes + 3) / 4;  // agg blocks (4 node-waves each)
    int nscan    = (n_nodes + 1023) / 1024;   // scan blocks (<= 64)

    char* ws = (char*)d_ws;
    size_t off = 0;
    auto alloc = [&](size_t bytes) {
        void* p = ws + off;
        off = (off + bytes + 255) & ~(size_t)255;
        return p;
    };
    unsigned short* m_accb = (unsigned short*)alloc((size_t)n_nodes * SD * 2);
    unsigned short* hbA = (unsigned short*)alloc((size_t)n_nodes * SD * 2);
    unsigned short* hbB = (unsigned short*)alloc((size_t)n_nodes * SD * 2);
    unsigned short* Ab0 = (unsigned short*)alloc((size_t)n_nodes * SD * 2);
    unsigned short* Bb0 = (unsigned short*)alloc((size_t)n_nodes * SD * 2);
    unsigned short* Ab1 = (unsigned short*)alloc((size_t)n_nodes * SD * 2);
    unsigned short* Bb1 = (unsigned short*)alloc((size_t)n_nodes * SD * 2);
    unsigned short* Cb  = (unsigned short*)alloc((size_t)(Lmax + 32) * SD * 2);
    int*   row_ptr      = (int*)alloc((size_t)(n_nodes + 1) * sizeof(int));
    int*   bsum         = (int*)alloc(64 * sizeof(int));
    // contiguous zero-init region: deg, fillc, eid, src_csr (one memset)
    char*  zbase        = (char*)alloc(0);
    int*   deg          = (int*)alloc((size_t)n_nodes * sizeof(int));
    int*   fillc        = (int*)alloc((size_t)n_nodes * sizeof(int));
    int*   eid          = (int*)alloc((size_t)(Lmax + 32) * sizeof(int));
    int*   src_csr      = (int*)alloc((size_t)(Lmax + 32) * sizeof(int));
    char*  zend         = (char*)alloc(0);
    unsigned short* WabT = (unsigned short*)alloc(128*64*2);
    unsigned short* WiT  = (unsigned short*)alloc(192*64*2);
    unsigned short* WhT  = (unsigned short*)alloc(192*64*2);
    unsigned short* W3T  = (unsigned short*)alloc(64*32*2);
    unsigned short* WeT  = (unsigned short*)alloc(64*32*2);
    (void)ws_size; (void)n_in;

    hipMemsetAsync(zbase, 0, (size_t)(zend - zbase), stream);

    prep_hist_kernel<<<96 + (n_edges + 255)/256, 256, 0, stream>>>(
        W_msg, W_i, W_h, W_embed, WabT, WiT, WhT, W3T, WeT, edge_dst, deg, n_edges);

    scan1_kernel<<<nscan, 256, 0, stream>>>(deg, bsum, n_nodes);
    scan2_kernel<<<1, 64, 0, stream>>>(bsum, nscan);
    scan3_kernel<<<nscan, 256, 0, stream>>>(deg, bsum, row_ptr, n_nodes);

    fill_kernel<<<(n_edges + 255)/256, 256, 0, stream>>>(edge_dst, edge_src, row_ptr,
                                                         fillc, eid, src_csr, n_edges);

    int ecblocks = ((Lmax + 15)/16 + 3) / 4;
    edge_embed_kernel<<<ecblocks + mtiles16, 256, 0, stream>>>(
        eid, edge_data, W3T, Cb, Lmax, ecblocks,
        node_data, WeT, b_embed, hbA, WabT, b_msg, Ab0, Bb0,
        (float*)d_out, b_r2, n_nodes);

    // it0
    agg_kernel<1><<<ntiles4, 256, 0, stream>>>(Ab0, Bb0, Cb, src_csr, row_ptr, deg,
                                               m_accb, n_nodes);
    gru_kernel<0><<<mtiles16, 256, 0, stream>>>(hbA, hbB, m_accb, Ab1, Bb1,
        WiT, WhT, b_i, b_h, WabT, b_msg, W_r1, b_r1, W_r2, (float*)d_out, n_nodes);
    // it1
    agg_kernel<0><<<ntiles4, 256, 0, stream>>>(Ab1, Bb1, Cb, src_csr, row_ptr, deg,
                                               m_accb, n_nodes);
    gru_kernel<0><<<mtiles16, 256, 0, stream>>>(hbB, hbA, m_accb, Ab0, Bb0,
        WiT, WhT, b_i, b_h, WabT, b_msg, W_r1, b_r1, W_r2, (float*)d_out, n_nodes);
    // it2 (LAST)
    agg_kernel<0><<<ntiles4, 256, 0, stream>>>(Ab0, Bb0, Cb, src_csr, row_ptr, deg,
                                               m_accb, n_nodes);
    gru_kernel<1><<<mtiles16, 256, 0, stream>>>(hbA, hbB, m_accb, Ab1, Bb1,
        WiT, WhT, b_i, b_h, WabT, b_msg, W_r1, b_r1, W_r2, (float*)d_out, n_nodes);
}